// Round 1
// baseline (144.342 us; speedup 1.0000x reference)
//
#include <hip/hip_runtime.h>

// MoGeSampledLocalLoss: per-patch truncated robust affine depth alignment +
// smooth-L1 loss, global mean over valid patches.
//
// Layout insight: x.reshape(B,P,K) with flat (B, P*K) means patch `g = b*P+p`
// owns flat elements [g*K, (g+1)*K). One 64-lane wave per patch; K=256 -> 4
// pixels/lane held in registers across all three passes (no memory re-reads).

#define WPB 4       // waves (patches) per 256-thread block
#define NSLOTS 64   // scatter slots for the global atomic reduction

__device__ __forceinline__ float wred(float v) {
  // 64-lane butterfly: every lane ends with the full sum.
  #pragma unroll
  for (int off = 32; off; off >>= 1) v += __shfl_xor(v, off, 64);
  return v;
}

__global__ void zero_ws_kernel(float* ws) {
  int i = threadIdx.x;
  if (i < 2 * NSLOTS) ws[i] = 0.0f;
}

__global__ __launch_bounds__(256) void moge_patch_kernel(
    const float* __restrict__ xg,   // pred_depth (B*N)
    const float* __restrict__ yg,   // gt_depth   (B*N)
    const int*   __restrict__ mg,   // mask       (B*N), 0/1
    const float* __restrict__ gsg,  // global_scale (B)
    const int*   __restrict__ pP,   // num_patches (device scalar)
    const int*   __restrict__ pK,   // patch_pixel_count (device scalar)
    int B,
    float* __restrict__ ws) {
  const int P = pP[0];
  const int K = pK[0];
  const int lane = threadIdx.x & 63;
  const int wib  = threadIdx.x >> 6;
  const int total_patches = B * P;
  const int wave_stride = gridDim.x * WPB;
  const float invK = 1.0f / (float)K;
  const bool fast = (K == 256);

  for (int patch = blockIdx.x * WPB + wib; patch < total_patches;
       patch += wave_stride) {
    const long base = (long)patch * (long)K;
    const float* xp = xg + base;
    const float* yp = yg + base;
    const int*   mp = mg + base;

    float xr[4], yr[4], mr[4], wr[4];

    // ---- pass 1: WLS sums + mask stats -------------------------------
    float sw = 0.f, swx = 0.f, swy = 0.f, swxx = 0.f, swxy = 0.f;
    float msum = 0.f, symsum = 0.f;
    if (fast) {
      const float4 x4 = *(const float4*)(xp + lane * 4);
      const float4 y4 = *(const float4*)(yp + lane * 4);
      const int4   m4 = *(const int4*)(mp + lane * 4);
      xr[0] = x4.x; xr[1] = x4.y; xr[2] = x4.z; xr[3] = x4.w;
      yr[0] = y4.x; yr[1] = y4.y; yr[2] = y4.z; yr[3] = y4.w;
      mr[0] = m4.x ? 1.f : 0.f; mr[1] = m4.y ? 1.f : 0.f;
      mr[2] = m4.z ? 1.f : 0.f; mr[3] = m4.w ? 1.f : 0.f;
      #pragma unroll
      for (int i = 0; i < 4; ++i) {
        const float m = mr[i], xx = xr[i], yy = yr[i];
        const float w = m / fmaxf(yy, 1e-5f);
        wr[i] = w;
        sw += w; swx += w * xx; swy += w * yy;
        swxx += w * xx * xx; swxy += w * xx * yy;
        msum += m; symsum += m * yy;
      }
    } else {
      for (int j = lane; j < K; j += 64) {
        const float m = mp[j] ? 1.f : 0.f;
        const float xx = xp[j], yy = yp[j];
        const float w = m / fmaxf(yy, 1e-5f);
        sw += w; swx += w * xx; swy += w * yy;
        swxx += w * xx * xx; swxy += w * xx * yy;
        msum += m; symsum += m * yy;
      }
    }
    sw = wred(sw); swx = wred(swx); swy = wred(swy);
    swxx = wred(swxx); swxy = wred(swxy);
    msum = wred(msum); symsum = wred(symsum);

    float det = sw * swxx - swx * swx;
    if (fabsf(det) < 1e-12f) det = 1e-12f;   // jnp.where -> +1e-12 either sign
    const float s0 = (sw * swxy - swx * swy) / det;
    const float t0 = (swxx * swy - swx * swxy) / det;

    // ---- pass 2: truncated refit ------------------------------------
    float sw2 = 0.f, swx2 = 0.f, swy2 = 0.f, swxx2 = 0.f, swxy2 = 0.f;
    if (fast) {
      #pragma unroll
      for (int i = 0; i < 4; ++i) {
        const float xx = xr[i], yy = yr[i], w = wr[i];
        const float e = w * fabsf(s0 * xx + t0 - yy);
        const float w2 = (e < 1.0f) ? w : 0.f;   // TRUNC = 1.0, strict <
        sw2 += w2; swx2 += w2 * xx; swy2 += w2 * yy;
        swxx2 += w2 * xx * xx; swxy2 += w2 * xx * yy;
      }
    } else {
      for (int j = lane; j < K; j += 64) {
        const float m = mp[j] ? 1.f : 0.f;
        const float xx = xp[j], yy = yp[j];
        const float w = m / fmaxf(yy, 1e-5f);
        const float e = w * fabsf(s0 * xx + t0 - yy);
        const float w2 = (e < 1.0f) ? w : 0.f;
        sw2 += w2; swx2 += w2 * xx; swy2 += w2 * yy;
        swxx2 += w2 * xx * xx; swxy2 += w2 * xx * yy;
      }
    }
    sw2 = wred(sw2); swx2 = wred(swx2); swy2 = wred(swy2);
    swxx2 = wred(swxx2); swxy2 = wred(swxy2);

    if (sw2 > 1e-8f) {  // sum(w2) == sw2; fall back to pass-1 sums otherwise
      sw = sw2; swx = swx2; swy = swy2; swxx = swxx2; swxy = swxy2;
    }
    det = sw * swxx - swx * swx;
    if (fabsf(det) < 1e-12f) det = 1e-12f;
    const float s = (sw * swxy - swx * swy) / det;
    const float t = (swxx * swy - swx * swxy) / det;

    // ---- pass 3: smooth-L1 patch loss -------------------------------
    const float mean_depth = (msum > 0.f) ? (symsum / fmaxf(msum, 1.f)) : 1.f;
    const float yfloor = 0.1f * mean_depth;

    float lsum = 0.f;
    if (fast) {
      #pragma unroll
      for (int i = 0; i < 4; ++i) {
        const float xx = xr[i], yy = yr[i], m = mr[i];
        const float pw = m / fmaxf(yy, yfloor);
        const float err = fabsf(s * xx + t - yy) * pw;
        // BETA = 0.1: err<0.1 ? 0.5*err^2/0.1 : err-0.05
        lsum += (err < 0.1f) ? (5.0f * err * err) : (err - 0.05f);
      }
    } else {
      for (int j = lane; j < K; j += 64) {
        const float m = mp[j] ? 1.f : 0.f;
        const float xx = xp[j], yy = yp[j];
        const float pw = m / fmaxf(yy, yfloor);
        const float err = fabsf(s * xx + t - yy) * pw;
        lsum += (err < 0.1f) ? (5.0f * err * err) : (err - 0.05f);
      }
    }
    lsum = wred(lsum);
    const float patch_loss = lsum * invK;

    // ---- validity + scatter-reduced accumulation --------------------
    const float gs = gsg[patch / P];
    const float ratio = s / fmaxf(gs, 1e-12f);
    const bool gs_ok = (gs > 0.f) ? (ratio >= 0.1f && ratio <= 10.0f) : true;
    const bool valid = (msum * invK >= 0.3f) && (s > 0.f) && gs_ok;

    if (lane == 0 && valid) {
      const int slot = patch & (NSLOTS - 1);
      atomicAdd(&ws[slot], patch_loss);
      atomicAdd(&ws[NSLOTS + slot], 1.0f);
    }
  }
}

__global__ void finalize_kernel(const float* __restrict__ ws,
                                float* __restrict__ out) {
  const int lane = threadIdx.x;  // launched with 64 threads
  float l = wred(ws[lane]);
  float c = wred(ws[NSLOTS + lane]);
  if (lane == 0) out[0] = (c > 0.f) ? (l / fmaxf(c, 1.f)) : 0.f;
}

extern "C" void kernel_launch(void* const* d_in, const int* in_sizes, int n_in,
                              void* d_out, int out_size, void* d_ws, size_t ws_size,
                              hipStream_t stream) {
  const float* pred = (const float*)d_in[0];
  const float* gt   = (const float*)d_in[1];
  const int*   mask = (const int*)d_in[2];
  const float* gs   = (const float*)d_in[3];
  const int*   pP   = (const int*)d_in[4];
  const int*   pK   = (const int*)d_in[5];
  const int B = in_sizes[3];
  const long total_pixels = (long)in_sizes[0];
  float* ws = (float*)d_ws;

  zero_ws_kernel<<<1, 128, 0, stream>>>(ws);

  // Grid assumes K=256 (one patch per wave); grid-stride loop + generic path
  // keep it correct for any K read on device.
  long est_patches = total_pixels / 256;
  int blocks = (int)((est_patches + WPB - 1) / WPB);
  if (blocks < 1) blocks = 1;
  moge_patch_kernel<<<blocks, 256, 0, stream>>>(pred, gt, mask, gs, pP, pK, B, ws);

  finalize_kernel<<<1, 64, 0, stream>>>(ws, (float*)d_out);
}